// Round 11
// baseline (1412.376 us; speedup 1.0000x reference)
//
#include <hip/hip_runtime.h>

typedef unsigned short u16;
typedef unsigned int   u32;
typedef unsigned long long u64;
typedef short short8 __attribute__((ext_vector_type(8)));
typedef float f32x4  __attribute__((ext_vector_type(4)));

__device__ __forceinline__ u16 f2bf(float f){
  u32 u = __float_as_uint(f);
  u32 r = (u + 0x7fffu + ((u >> 16) & 1u)) >> 16;
  return (u16)r;
}
__device__ __forceinline__ float lrn_one(float v, float pv){
  float avg = 0.5f*(v*v + pv*pv);
  float d = 1.0f + 2e-5f*avg;
  return v * exp2f(-0.75f * log2f(d));   // d >= 1, safe
}

// ---------------- K0a: prepack w5 fp32 [1024][64][16][16] -> bf16 fragment order
// Wpk5[ocb(8)][chunk(32)][kx(16)][quad(4)][oc128(128)][j(8)]
__global__ __launch_bounds__(256) void k0w5(const float* __restrict__ w5, u16* __restrict__ wpk){
  int idx = blockIdx.x*256 + threadIdx.x;            // 16,777,216
  int j     =  idx        & 7;
  int oc128 = (idx >> 3)  & 127;
  int quad  = (idx >> 10) & 3;
  int kx    = (idx >> 12) & 15;
  int chunk = (idx >> 16) & 31;
  int ocb   =  idx >> 21;
  int oc = ocb*128 + oc128;
  int ic = chunk*2 + (quad>>1);
  int ky = (quad&1)*8 + j;
  wpk[idx] = f2bf(w5[((oc*64 + ic)*16 + ky)*16 + kx]);
}

// ---------------- K0b v2: prepack w6 fp32[1024][1024] -> bf16 fragment order
// W6pk[mb(8)][kc(8)][kk(4)][quad(4)][oc128(128)][j(8)]  (coalesced af loads in k8a)
__global__ __launch_bounds__(256) void k0w6(const float* __restrict__ w6, u16* __restrict__ wpk){
  int idx = blockIdx.x*256 + threadIdx.x;            // 1,048,576
  int j     =  idx        & 7;
  int oc128 = (idx >> 3)  & 127;
  int quad  = (idx >> 10) & 3;
  int kk    = (idx >> 12) & 3;
  int kc    = (idx >> 14) & 7;
  int mb    =  idx >> 17;
  int oc = mb*128 + oc128;
  int ic = kc*128 + kk*32 + quad*8 + j;
  wpk[idx] = f2bf(w6[oc*1024 + ic]);
}

// ---------------- K0c: zero the k8 accumulation buffer (18432 f32)
__global__ __launch_bounds__(256) void k0z(float* __restrict__ accum){
  int idx = blockIdx.x*256 + threadIdx.x;
  if (idx < 18432) accum[idx] = 0.f;
}

// ---------------- K1: conv 7x7, 1->64, SAME pad 3, relu
__global__ __launch_bounds__(256) void k1_conv7x7(const float* __restrict__ x, const float* __restrict__ w1,
                                                  const float* __restrict__ b1, float* __restrict__ out){
  int idx = blockIdx.x*256 + threadIdx.x;            // 2,097,152
  int ox = idx & 127, oy = (idx>>7)&127, oc = (idx>>14)&63, n = idx>>20;
  float acc = b1[oc];
  const float* wb = w1 + oc*49;
  const float* xb = x + n*16384;
  #pragma unroll
  for (int ky=0;ky<7;++ky){
    int y = oy + ky - 3;
    if ((unsigned)y < 128u){
      #pragma unroll
      for (int kx=0;kx<7;++kx){
        int xx = ox + kx - 3;
        if ((unsigned)xx < 128u)
          acc += wb[ky*7+kx] * xb[y*128+xx];
      }
    }
  }
  out[idx] = acc > 0.f ? acc : 0.f;
}

// ---------------- K2 v4: conv 5x5, 64->64, SAME pad 2, relu. 8 oc per block.
__global__ __launch_bounds__(256) void k2_conv5x5(const float* __restrict__ in, const float* __restrict__ w2,
                                                  const float* __restrict__ b2, float* __restrict__ out){
  __shared__ __align__(16) float t[720];             // 20 rows x 36 cols
  __shared__ float wl[200];                          // 8 oc x 25
  int bid = blockIdx.x;
  int colg = bid & 3;
  int rowg = (bid >> 2) & 7;
  int ocg  = (bid >> 5) & 7;
  int n    =  bid >> 8;
  int tid = threadIdx.x;
  int oy0 = rowg*16, ox0 = colg*32;
  int r = tid >> 4, c0 = (tid & 15)*2;
  float acc[8][2];
  #pragma unroll
  for (int o=0;o<8;++o){ acc[o][0]=0.f; acc[o][1]=0.f; }

  for (int ic=0; ic<64; ++ic){
    __syncthreads();
    for (int u=tid; u<720; u+=256){
      int rr = u/36, cc = u - rr*36;
      int gy = oy0+rr-2, gx = ox0+cc-2;
      t[u] = ((unsigned)gy<128u && (unsigned)gx<128u) ? in[((n*64+ic)*128+gy)*128+gx] : 0.f;
    }
    if (tid < 200) wl[tid] = w2[((ocg*8 + tid/25)*64 + ic)*25 + (tid%25)];
    __syncthreads();
    #pragma unroll
    for (int ky=0;ky<5;++ky){
      float2 a = *(const float2*)&t[(r+ky)*36 + c0];
      float2 b = *(const float2*)&t[(r+ky)*36 + c0 + 2];
      float2 c = *(const float2*)&t[(r+ky)*36 + c0 + 4];
      float f[6] = {a.x,a.y,b.x,b.y,c.x,c.y};
      #pragma unroll
      for (int o=0;o<8;++o){
        #pragma unroll
        for (int kx=0;kx<5;++kx){
          float wv = wl[o*25 + ky*5 + kx];
          acc[o][0] += wv * f[kx];
          acc[o][1] += wv * f[kx+1];
        }
      }
    }
  }
  #pragma unroll
  for (int o=0;o<8;++o){
    float bb = b2[ocg*8 + o];
    float2 st;
    st.x = fmaxf(acc[o][0]+bb, 0.f);
    st.y = fmaxf(acc[o][1]+bb, 0.f);
    *(float2*)&out[((n*64 + ocg*8 + o)*128 + oy0+r)*128 + ox0 + c0] = st;
  }
}

// ---------------- K3: LRN + 4-crop + 2x2 maxpool
__global__ __launch_bounds__(256) void k3_lrn_crop_pool(const float* __restrict__ h, float* __restrict__ out){
  int idx = blockIdx.x*256 + threadIdx.x;            // 2,032,128
  int j = idx % 63; int t1 = idx / 63;
  int i = t1 % 63; int t2 = t1 / 63;
  int c = t2 & 63; int b = t2 >> 6;
  int v = b >> 1, n = b & 1;
  int r0 = v & 1, c0 = v >> 1;
  const float* base  = h + ((n*64+c  )*128)*128;
  const float* basep = h + ((n*64+c-1)*128)*128;
  float m = -3.4e38f;
  #pragma unroll
  for (int a=0;a<2;++a)
    #pragma unroll
    for (int bb=0;bb<2;++bb){
      int y = r0+2*i+a, xx = c0+2*j+bb;
      float val = base[y*128+xx];
      float pv  = c ? basep[y*128+xx] : 0.f;
      m = fmaxf(m, lrn_one(val, pv));
    }
  out[idx] = m;
}

// ---------------- K4/K5 v3: conv 3x3, 64->64, SAME pad 1, relu. 8 oc per block.
__global__ __launch_bounds__(256) void k_conv3x3(const float* __restrict__ in, const float* __restrict__ w,
                                                 const float* __restrict__ bias, float* __restrict__ out){
  __shared__ __align__(16) float t[408];             // 6 rows x 68 (66 used)
  __shared__ float wl[72];                           // 8 oc x 9
  int bid = blockIdx.x;
  int rowg = bid & 15;
  int ocg  = (bid >> 4) & 7;
  int b    =  bid >> 7;
  int tid = threadIdx.x;
  int r = tid >> 6, cx = tid & 63;                   // 4 rows x 64 cols (col 63 masked)
  int oy0 = rowg*4;
  float acc[8];
  #pragma unroll
  for (int o=0;o<8;++o) acc[o] = 0.f;

  for (int ic=0; ic<64; ++ic){
    __syncthreads();
    #pragma unroll
    for (int u0=0; u0<2; ++u0){
      int u = tid + u0*256;
      if (u < 408){
        int rr = u/68, cc = u - rr*68;
        int gy = oy0+rr-1, gx = cc-1;
        t[u] = (cc<66 && (unsigned)gy<63u && (unsigned)gx<63u) ? in[((b*64+ic)*63+gy)*63+gx] : 0.f;
      }
    }
    if (tid < 72) wl[tid] = w[((ocg*8 + tid/9)*64 + ic)*9 + (tid%9)];
    __syncthreads();
    #pragma unroll
    for (int ky=0;ky<3;++ky){
      float a0 = t[(r+ky)*68 + cx];
      float a1 = t[(r+ky)*68 + cx + 1];
      float a2 = t[(r+ky)*68 + cx + 2];
      #pragma unroll
      for (int o=0;o<8;++o){
        acc[o] += wl[o*9+ky*3  ]*a0;
        acc[o] += wl[o*9+ky*3+1]*a1;
        acc[o] += wl[o*9+ky*3+2]*a2;
      }
    }
  }
  int oy = oy0 + r;
  if (oy < 63 && cx < 63){
    #pragma unroll
    for (int o=0;o<8;++o){
      float v = acc[o] + bias[ocg*8+o];
      out[((b*64 + ocg*8 + o)*63 + oy)*63 + cx] = v > 0.f ? v : 0.f;
    }
  }
}

// ---------------- K6: LRN elementwise, f32 (8,64,63,63) -> bf16 padded (8,64,64,64)
__global__ __launch_bounds__(256) void k6_lrn_bf(const float* __restrict__ in, u16* __restrict__ outb){
  int idx = blockIdx.x*256+threadIdx.x;              // 2,097,152
  int col = idx & 63, iy = (idx>>6)&63, ic = (idx>>12)&63, b = idx>>18;
  u16 o = 0;
  if (col < 63 && iy < 63){
    int src = ((b*64+ic)*63 + iy)*63 + col;
    float v  = in[src];
    float pv = ic ? in[src - 3969] : 0.f;
    o = f2bf(lrn_one(v, pv));
  }
  outb[idx] = o;
}

// ---------------- K7z: conv 16x16 VALID via MFMA implicit GEMM.
// k7u structure halved again: 32 oc x 96 px per block, acc[2][6]=48 AGPR,
// af slots shrink to 2 frags (ring-4 = af[4][2], 32 VGPR) -> per-wave regs
// ~150 <= 170 (512/3) -> 3 waves/SIMD, 4 blocks/CU (waves from different
// blocks cover each other's staging barriers). af prefetch distance 2->3
// (zero reg cost; 16%4==0 keeps cross-chunk ring phase; tail reads land in
// allocated workspace, dead). Math bit-identical to k7u. Grid 2048.
__global__ __launch_bounds__(192, 1) void k7z(const u16* __restrict__ inb, const u16* __restrict__ wpk,
                                              const float* __restrict__ b5, u16* __restrict__ y5){
  __shared__ __align__(16) u16 itile[7168];          // 14,336 B
  int bid = blockIdx.x;
  int ochh = bid & 31;                               // 32-oc group
  int rem = bid >> 5;
  int n8  = rem & 7;
  int r   = rem >> 3;                                // 0..7
  int tid = threadIdx.x;
  int w = tid / 64, lane = tid & 63, quad = lane >> 4, m = lane & 15;
  int ic2q = quad >> 1, kyh = quad & 1;

  f32x4 acc[2][6];
  #pragma unroll
  for (int tm=0;tm<2;++tm)
    #pragma unroll
    for (int t=0;t<6;++t) acc[tm][t] = (f32x4){0.f,0.f,0.f,0.f};

  const u16* gin    = inb + ((size_t)n8 * 64) * 4096;
  // ocb = ochh>>2 selects the 128-oc weight block; (ochh&3)*32 is the oc128 base
  const u16* wblock = wpk + ((size_t)(ochh >> 2) << 21) + (ochh & 3)*256;
  const u16* wbase  = wblock + quad*1024 + m*8;

  // single LDS base; per-t/kx deltas are compile-time immediates:
  // u16 offset = (t%3)*128 + (t/3)*512 + kx*8
  int bb = ((ic2q*7 + (2*w + kyh))*64 + m)*8;

  short8 af[4][2];                                   // ring-4, distance-3
  short8 bf[2][6];
  // preload chunk-0 kx=0,1,2 weights
  #pragma unroll
  for (int q=0;q<2;++q) af[0][q] = *(const short8*)(wbase + q*128);
  #pragma unroll
  for (int q=0;q<2;++q) af[1][q] = *(const short8*)(wbase + 4096 + q*128);
  #pragma unroll
  for (int q=0;q<2;++q) af[2][q] = *(const short8*)(wbase + 8192 + q*128);

  #pragma unroll 1
  for (int chunk=0; chunk<32; ++chunk){
    __syncthreads();
    // stage 2 ic x 56 rows x 64 cols, transposed into [ic2][win][col][j]
    {
      const u16* gq = gin + (size_t)(chunk*2)*4096 + r*64;
      for (int v = tid; v < 1792; v += 192){           // 2 ic x 28 iy-pairs x 32 col-pairs
        int cp  = v & 31;
        int t2  = v >> 5;                              // 0..55
        int iyp = t2 % 28;
        int ic2 = t2 / 28;
        int iy0 = iyp*2;
        const u16* g = gq + ic2*4096 + iy0*64 + 2*cp;
        u32 d0 = *(const u32*)(g);
        u32 d1 = *(const u32*)(g + 64);
        u32 lo = (d0 & 0xffffu) | (d1 << 16);          // col 2cp:   rows iy0, iy0+1
        u32 hi = (d0 >> 16) | (d1 & 0xffff0000u);      // col 2cp+1
        int win = iy0 >> 3, j = iy0 & 7;
        int base = ((ic2*7 + win)*64 + 2*cp)*8 + j;
        *(u32*)&itile[base]     = lo;
        *(u32*)&itile[base + 8] = hi;
      }
    }
    __syncthreads();
    const u16* wk0  = wbase + (chunk << 16);
    const u16* bptr = itile + bb;

    // bf for kx=0 of this chunk
    #pragma unroll
    for (int t=0;t<6;++t) bf[0][t] = *(const short8*)(bptr + (t%3)*128 + (t/3)*512);

    #pragma unroll
    for (int kx=0; kx<16; ++kx){
      // af prefetch for kx+3 (crosses into next chunk at kx=13,14,15; 16%4==0
      // keeps ring phase aligned; chunk=31 tail reads land in adjacent
      // workspace (next ocb block / W6pk) and are dead).
      #pragma unroll
      for (int q=0;q<2;++q) af[(kx+3)&3][q] = *(const short8*)(wk0 + (kx+3)*4096 + q*128);
      // bf prefetch for kx+1
      if (kx < 15){
        #pragma unroll
        for (int t=0;t<6;++t) bf[(kx+1)&1][t] = *(const short8*)(bptr + (t%3)*128 + (t/3)*512 + (kx+1)*8);
      }
      __builtin_amdgcn_s_setprio(1);
      #pragma unroll
      for (int q=0;q<2;++q)
        #pragma unroll
        for (int t=0;t<6;++t)
          acc[q][t] = __builtin_amdgcn_mfma_f32_16x16x32_bf16(af[kx&3][q], bf[kx&1][t], acc[q][t], 0, 0, 0);
      __builtin_amdgcn_s_setprio(0);
    }
  }

  #pragma unroll
  for (int tm=0;tm<2;++tm){
    #pragma unroll
    for (int rr=0;rr<4;++rr){
      int oc = ochh*32 + tm*16 + quad*4 + rr;
      float bias = b5[oc];
      #pragma unroll
      for (int t=0;t<6;++t){
        int row = r + 16*w + 8*(t/3);
        int ox  = (t%3)*16 + m;
        float v = acc[tm][t][rr] + bias;
        v = v>0.f ? v : 0.f;
        y5[(((size_t)n8*1024 + oc)*48 + row)*48 + ox] = f2bf(v);
      }
    }
  }
}

// ---------------- K8a: 1x1 conv (1024->1024) MFMA + relu + w7-dot + block reduce + atomicAdd
__global__ __launch_bounds__(128) void k8a(const u16* __restrict__ y5, const u16* __restrict__ w6pk,
                                           const float* __restrict__ b6, const float* __restrict__ w7,
                                           float* __restrict__ accum){
  __shared__ __align__(16) u16 btile[96*136];        // 26,112 B
  __shared__ float red[8*96];
  int bid = blockIdx.x;
  int mb = bid & 7;
  int r  = bid >> 3;
  int n8 = r / 24, rp = r % 24;
  int r0 = 2*rp;
  int tid = threadIdx.x;
  int w = tid >> 6, lane = tid & 63, quad = lane >> 4, m = lane & 15;

  f32x4 acc[4][6];
  #pragma unroll
  for (int tm=0;tm<4;++tm)
    #pragma unroll
    for (int t=0;t<6;++t) acc[tm][t] = (f32x4){0.f,0.f,0.f,0.f};

  #pragma unroll 1
  for (int kc=0; kc<8; ++kc){
    __syncthreads();
    for (int u=tid; u<6144; u+=128){                 // 128 ic x 48 px-pairs
      int pp = u % 48; int ic2 = u / 48;
      int rowl = pp / 24; int ox0 = (pp % 24)*2;
      u32 val = *(const u32*)(y5 + (((size_t)(n8*1024 + kc*128 + ic2)*48) + r0 + rowl)*48 + ox0);
      int px = rowl*48 + ox0;
      btile[(px  )*136 + ic2] = (u16)(val & 0xffffu);
      btile[(px+1)*136 + ic2] = (u16)(val >> 16);
    }
    __syncthreads();
    for (int kk=0; kk<4; ++kk){
      short8 af[4];
      #pragma unroll
      for (int tm=0;tm<4;++tm)
        af[tm] = *(const short8*)(w6pk + (size_t)((((mb*8 + kc)*4 + kk)*4 + quad)*128 + (w*64 + tm*16 + m))*8);
      short8 bf[6];
      #pragma unroll
      for (int t=0;t<6;++t){
        int pxl = ((t>=3)?48:0) + (t%3)*16 + m;
        bf[t] = *(const short8*)(btile + pxl*136 + kk*32 + quad*8);
      }
      #pragma unroll
      for (int tm=0;tm<4;++tm)
        #pragma unroll
        for (int t=0;t<6;++t)
          acc[tm][t] = __builtin_amdgcn_mfma_f32_16x16x32_bf16(af[tm], bf[t], acc[tm][t], 0, 0, 0);
    }
  }
  float part[6];
  #pragma unroll
  for (int t=0;t<6;++t) part[t]=0.f;
  #pragma unroll
  for (int tm=0;tm<4;++tm){
    #pragma unroll
    for (int rr=0;rr<4;++rr){
      int oc = mb*128 + w*64 + tm*16 + quad*4 + rr;
      float bb = b6[oc];
      float ww = w7[oc];
      #pragma unroll
      for (int t=0;t<6;++t){
        float z = acc[tm][t][rr] + bb;
        z = z>0.f ? z : 0.f;
        part[t] += ww*z;
      }
    }
  }
  #pragma unroll
  for (int t=0;t<6;++t){
    int pxl = ((t>=3)?48:0) + (t%3)*16 + m;
    red[(w*4+quad)*96 + pxl] = part[t];
  }
  __syncthreads();
  if (tid < 96){
    float s = 0.f;
    #pragma unroll
    for (int k=0;k<8;++k) s += red[k*96 + tid];
    int rowl = tid / 48, ox = tid % 48;
    atomicAdd(&accum[((size_t)n8*48 + r0 + rowl)*48 + ox], s);
  }
}

// ---------------- K8b: sigmoid + interweave. accum (8,48,48) -> out (2,1,96,96) f32
__global__ __launch_bounds__(256) void k8b(const float* __restrict__ accum, const float* __restrict__ b7,
                                           float* __restrict__ out){
  int idx = blockIdx.x*256 + threadIdx.x;
  if (idx >= 18432) return;
  int n8 = idx / 2304; int rem = idx % 2304;
  int oy = rem / 48, ox = rem % 48;
  float s = accum[idx] + b7[0];
  float sig = 1.f / (1.f + expf(-s));
  int v = n8 >> 1, n = n8 & 1;
  int a = v & 1, bcol = v >> 1;
  out[((size_t)n*96 + 2*oy + a)*96 + 2*ox + bcol] = sig;
}

extern "C" void kernel_launch(void* const* d_in, const int* in_sizes, int n_in,
                              void* d_out, int out_size, void* d_ws, size_t ws_size,
                              hipStream_t stream){
  const float* x  = (const float*)d_in[0];
  const float* w1 = (const float*)d_in[1];
  const float* b1 = (const float*)d_in[2];
  const float* w2 = (const float*)d_in[3];
  const float* b2 = (const float*)d_in[4];
  const float* w3 = (const float*)d_in[5];
  const float* b3 = (const float*)d_in[6];
  const float* w4 = (const float*)d_in[7];
  const float* b4 = (const float*)d_in[8];
  const float* w5 = (const float*)d_in[9];
  const float* b5 = (const float*)d_in[10];
  const float* w6 = (const float*)d_in[11];
  const float* b6 = (const float*)d_in[12];
  const float* w7 = (const float*)d_in[13];
  const float* b7 = (const float*)d_in[14];
  float* ws = (float*)d_ws;
  float* out = (float*)d_out;

  // single verified layout (<= 82 MB):
  // C [0, 2,097,152) f32 ; Cb (u16) over C ; A [2,097,152, 4,194,304) ; B [4,194,304, 6,291,456)
  // F (u16) [2,097,152, 11,534,336) over dead A/B ; Wpk5 (u16) [11,534,336, 19,922,944)
  // W6pk (u16) [19,922,944, 20,447,232) ; accum [20,447,232, 20,465,664)
  float* C  = ws;
  u16*   Cb = (u16*)ws;
  float* A  = ws + 2097152;
  float* B  = ws + 4194304;
  u16*   F    = (u16*)(ws + 2097152);
  u16*   Wpk5 = (u16*)(ws + 11534336);
  u16*   W6pk = (u16*)(ws + 19922944);
  float* accum = ws + 20447232;

  hipLaunchKernelGGL(k0w5,            dim3(65536), dim3(256), 0, stream, w5, Wpk5);
  hipLaunchKernelGGL(k0w6,            dim3(4096),  dim3(256), 0, stream, w6, W6pk);
  hipLaunchKernelGGL(k0z,             dim3(72),    dim3(256), 0, stream, accum);
  hipLaunchKernelGGL(k1_conv7x7,      dim3(8192),  dim3(256), 0, stream, x, w1, b1, A);
  hipLaunchKernelGGL(k2_conv5x5,      dim3(512),   dim3(256), 0, stream, A, w2, b2, B);
  hipLaunchKernelGGL(k3_lrn_crop_pool,dim3(7938),  dim3(256), 0, stream, B, C);
  hipLaunchKernelGGL(k_conv3x3,       dim3(1024),  dim3(256), 0, stream, C, w3, b3, A);
  hipLaunchKernelGGL(k_conv3x3,       dim3(1024),  dim3(256), 0, stream, A, w4, b4, B);
  hipLaunchKernelGGL(k6_lrn_bf,       dim3(8192),  dim3(256), 0, stream, B, Cb);
  hipLaunchKernelGGL(k7z,             dim3(2048),  dim3(192), 0, stream, Cb, Wpk5, b5, F);
  hipLaunchKernelGGL(k8a,             dim3(1536),  dim3(128), 0, stream, F, W6pk, b6, w7, accum);
  hipLaunchKernelGGL(k8b,             dim3(72),    dim3(256), 0, stream, accum, b7, out);
}

// Round 12
// 1331.401 us; speedup vs baseline: 1.0608x; 1.0608x over previous
//
#include <hip/hip_runtime.h>

typedef unsigned short u16;
typedef unsigned int   u32;
typedef unsigned long long u64;
typedef short short8 __attribute__((ext_vector_type(8)));
typedef float f32x4  __attribute__((ext_vector_type(4)));

__device__ __forceinline__ u16 f2bf(float f){
  u32 u = __float_as_uint(f);
  u32 r = (u + 0x7fffu + ((u >> 16) & 1u)) >> 16;
  return (u16)r;
}
__device__ __forceinline__ float lrn_one(float v, float pv){
  float avg = 0.5f*(v*v + pv*pv);
  float d = 1.0f + 2e-5f*avg;
  return v * exp2f(-0.75f * log2f(d));   // d >= 1, safe
}

// ---------------- K0all: fused prepack (w5, w6) + accum zero. Uniform branch on block range.
// b < 65536          : Wpk5[ocb(8)][chunk(32)][kx(16)][quad(4)][oc128(128)][j(8)]
// b < 65536+4096     : W6pk[mb(8)][kc(8)][kk(4)][quad(4)][oc128(128)][j(8)]
// else (72 blocks)   : zero accum (18432 f32)
__global__ __launch_bounds__(256) void k0all(const float* __restrict__ w5, u16* __restrict__ wpk5,
                                             const float* __restrict__ w6, u16* __restrict__ wpk6,
                                             float* __restrict__ accum){
  int b = blockIdx.x;
  if (b < 65536){
    int idx = b*256 + threadIdx.x;                   // 16,777,216
    int j     =  idx        & 7;
    int oc128 = (idx >> 3)  & 127;
    int quad  = (idx >> 10) & 3;
    int kx    = (idx >> 12) & 15;
    int chunk = (idx >> 16) & 31;
    int ocb   =  idx >> 21;
    int oc = ocb*128 + oc128;
    int ic = chunk*2 + (quad>>1);
    int ky = (quad&1)*8 + j;
    wpk5[idx] = f2bf(w5[((oc*64 + ic)*16 + ky)*16 + kx]);
  } else if (b < 65536 + 4096){
    int idx = (b - 65536)*256 + threadIdx.x;         // 1,048,576
    int j     =  idx        & 7;
    int oc128 = (idx >> 3)  & 127;
    int quad  = (idx >> 10) & 3;
    int kk    = (idx >> 12) & 3;
    int kc    = (idx >> 14) & 7;
    int mb    =  idx >> 17;
    int oc = mb*128 + oc128;
    int ic = kc*128 + kk*32 + quad*8 + j;
    wpk6[idx] = f2bf(w6[oc*1024 + ic]);
  } else {
    int idx = (b - 65536 - 4096)*256 + threadIdx.x;
    if (idx < 18432) accum[idx] = 0.f;
  }
}

// ---------------- K1: conv 7x7, 1->64, SAME pad 3, relu
__global__ __launch_bounds__(256) void k1_conv7x7(const float* __restrict__ x, const float* __restrict__ w1,
                                                  const float* __restrict__ b1, float* __restrict__ out){
  int idx = blockIdx.x*256 + threadIdx.x;            // 2,097,152
  int ox = idx & 127, oy = (idx>>7)&127, oc = (idx>>14)&63, n = idx>>20;
  float acc = b1[oc];
  const float* wb = w1 + oc*49;
  const float* xb = x + n*16384;
  #pragma unroll
  for (int ky=0;ky<7;++ky){
    int y = oy + ky - 3;
    if ((unsigned)y < 128u){
      #pragma unroll
      for (int kx=0;kx<7;++kx){
        int xx = ox + kx - 3;
        if ((unsigned)xx < 128u)
          acc += wb[ky*7+kx] * xb[y*128+xx];
      }
    }
  }
  out[idx] = acc > 0.f ? acc : 0.f;
}

// ---------------- K2 v4: conv 5x5, 64->64, SAME pad 2, relu. 8 oc per block.
__global__ __launch_bounds__(256) void k2_conv5x5(const float* __restrict__ in, const float* __restrict__ w2,
                                                  const float* __restrict__ b2, float* __restrict__ out){
  __shared__ __align__(16) float t[720];             // 20 rows x 36 cols
  __shared__ float wl[200];                          // 8 oc x 25
  int bid = blockIdx.x;
  int colg = bid & 3;
  int rowg = (bid >> 2) & 7;
  int ocg  = (bid >> 5) & 7;
  int n    =  bid >> 8;
  int tid = threadIdx.x;
  int oy0 = rowg*16, ox0 = colg*32;
  int r = tid >> 4, c0 = (tid & 15)*2;
  float acc[8][2];
  #pragma unroll
  for (int o=0;o<8;++o){ acc[o][0]=0.f; acc[o][1]=0.f; }

  for (int ic=0; ic<64; ++ic){
    __syncthreads();
    for (int u=tid; u<720; u+=256){
      int rr = u/36, cc = u - rr*36;
      int gy = oy0+rr-2, gx = ox0+cc-2;
      t[u] = ((unsigned)gy<128u && (unsigned)gx<128u) ? in[((n*64+ic)*128+gy)*128+gx] : 0.f;
    }
    if (tid < 200) wl[tid] = w2[((ocg*8 + tid/25)*64 + ic)*25 + (tid%25)];
    __syncthreads();
    #pragma unroll
    for (int ky=0;ky<5;++ky){
      float2 a = *(const float2*)&t[(r+ky)*36 + c0];
      float2 b = *(const float2*)&t[(r+ky)*36 + c0 + 2];
      float2 c = *(const float2*)&t[(r+ky)*36 + c0 + 4];
      float f[6] = {a.x,a.y,b.x,b.y,c.x,c.y};
      #pragma unroll
      for (int o=0;o<8;++o){
        #pragma unroll
        for (int kx=0;kx<5;++kx){
          float wv = wl[o*25 + ky*5 + kx];
          acc[o][0] += wv * f[kx];
          acc[o][1] += wv * f[kx+1];
        }
      }
    }
  }
  #pragma unroll
  for (int o=0;o<8;++o){
    float bb = b2[ocg*8 + o];
    float2 st;
    st.x = fmaxf(acc[o][0]+bb, 0.f);
    st.y = fmaxf(acc[o][1]+bb, 0.f);
    *(float2*)&out[((n*64 + ocg*8 + o)*128 + oy0+r)*128 + ox0 + c0] = st;
  }
}

// ---------------- K3: LRN + 4-crop + 2x2 maxpool
__global__ __launch_bounds__(256) void k3_lrn_crop_pool(const float* __restrict__ h, float* __restrict__ out){
  int idx = blockIdx.x*256 + threadIdx.x;            // 2,032,128
  int j = idx % 63; int t1 = idx / 63;
  int i = t1 % 63; int t2 = t1 / 63;
  int c = t2 & 63; int b = t2 >> 6;
  int v = b >> 1, n = b & 1;
  int r0 = v & 1, c0 = v >> 1;
  const float* base  = h + ((n*64+c  )*128)*128;
  const float* basep = h + ((n*64+c-1)*128)*128;
  float m = -3.4e38f;
  #pragma unroll
  for (int a=0;a<2;++a)
    #pragma unroll
    for (int bb=0;bb<2;++bb){
      int y = r0+2*i+a, xx = c0+2*j+bb;
      float val = base[y*128+xx];
      float pv  = c ? basep[y*128+xx] : 0.f;
      m = fmaxf(m, lrn_one(val, pv));
    }
  out[idx] = m;
}

// ---------------- K4 (v3): conv 3x3, 64->64, SAME pad 1, relu. 8 oc per block.
__global__ __launch_bounds__(256) void k_conv3x3(const float* __restrict__ in, const float* __restrict__ w,
                                                 const float* __restrict__ bias, float* __restrict__ out){
  __shared__ __align__(16) float t[408];             // 6 rows x 68 (66 used)
  __shared__ float wl[72];                           // 8 oc x 9
  int bid = blockIdx.x;
  int rowg = bid & 15;
  int ocg  = (bid >> 4) & 7;
  int b    =  bid >> 7;
  int tid = threadIdx.x;
  int r = tid >> 6, cx = tid & 63;                   // 4 rows x 64 cols (col 63 masked)
  int oy0 = rowg*4;
  float acc[8];
  #pragma unroll
  for (int o=0;o<8;++o) acc[o] = 0.f;

  for (int ic=0; ic<64; ++ic){
    __syncthreads();
    #pragma unroll
    for (int u0=0; u0<2; ++u0){
      int u = tid + u0*256;
      if (u < 408){
        int rr = u/68, cc = u - rr*68;
        int gy = oy0+rr-1, gx = cc-1;
        t[u] = (cc<66 && (unsigned)gy<63u && (unsigned)gx<63u) ? in[((b*64+ic)*63+gy)*63+gx] : 0.f;
      }
    }
    if (tid < 72) wl[tid] = w[((ocg*8 + tid/9)*64 + ic)*9 + (tid%9)];
    __syncthreads();
    #pragma unroll
    for (int ky=0;ky<3;++ky){
      float a0 = t[(r+ky)*68 + cx];
      float a1 = t[(r+ky)*68 + cx + 1];
      float a2 = t[(r+ky)*68 + cx + 2];
      #pragma unroll
      for (int o=0;o<8;++o){
        acc[o] += wl[o*9+ky*3  ]*a0;
        acc[o] += wl[o*9+ky*3+1]*a1;
        acc[o] += wl[o*9+ky*3+2]*a2;
      }
    }
  }
  int oy = oy0 + r;
  if (oy < 63 && cx < 63){
    #pragma unroll
    for (int o=0;o<8;++o){
      float v = acc[o] + bias[ocg*8+o];
      out[((b*64 + ocg*8 + o)*63 + oy)*63 + cx] = v > 0.f ? v : 0.f;
    }
  }
}

// ---------------- K5f: conv 3x3 (64->64) + relu + LRN + bf16 pack, fused (replaces k5+k6).
// Computes 9 channels (ocg*8-1 .. ocg*8+7) so LRN's ic-1 neighbor is in-block
// (+12.5% FMA). Writes Cb bf16 (8,64,64,64) padded layout directly, zeros at
// iy==63 / col==63 pad cells (threads cover oy,cx in 0..63 fully).
__global__ __launch_bounds__(256) void k5_fused(const float* __restrict__ in, const float* __restrict__ w,
                                                const float* __restrict__ bias, u16* __restrict__ outb){
  __shared__ __align__(16) float t[408];             // 6 rows x 68 (66 used)
  __shared__ float wl[81];                           // 9 ch x 9
  int bid = blockIdx.x;
  int rowg = bid & 15;
  int ocg  = (bid >> 4) & 7;
  int b    =  bid >> 7;
  int tid = threadIdx.x;
  int r = tid >> 6, cx = tid & 63;                   // 4 rows x 64 cols
  int oy0 = rowg*4;
  float acc[9];
  #pragma unroll
  for (int o=0;o<9;++o) acc[o] = 0.f;

  for (int ic=0; ic<64; ++ic){
    __syncthreads();
    #pragma unroll
    for (int u0=0; u0<2; ++u0){
      int u = tid + u0*256;
      if (u < 408){
        int rr = u/68, cc = u - rr*68;
        int gy = oy0+rr-1, gx = cc-1;
        t[u] = (cc<66 && (unsigned)gy<63u && (unsigned)gx<63u) ? in[((b*64+ic)*63+gy)*63+gx] : 0.f;
      }
    }
    if (tid < 81){
      int o = tid/9, k = tid - o*9;
      int c = ocg*8 - 1 + o;                         // channel index, may be -1
      wl[tid] = (c >= 0) ? w[(c*64 + ic)*9 + k] : 0.f;
    }
    __syncthreads();
    #pragma unroll
    for (int ky=0;ky<3;++ky){
      float a0 = t[(r+ky)*68 + cx];
      float a1 = t[(r+ky)*68 + cx + 1];
      float a2 = t[(r+ky)*68 + cx + 2];
      #pragma unroll
      for (int o=0;o<9;++o){
        acc[o] += wl[o*9+ky*3  ]*a0;
        acc[o] += wl[o*9+ky*3+1]*a1;
        acc[o] += wl[o*9+ky*3+2]*a2;
      }
    }
  }
  int oy = oy0 + r;                                  // 0..63
  bool valid = (oy < 63) && (cx < 63);
  #pragma unroll
  for (int o=0;o<8;++o){
    int c = ocg*8 + o;                               // output channel; acc idx o+1
    u16 ov = 0;
    if (valid){
      float v  = fmaxf(acc[o+1] + bias[c], 0.f);
      float pv = (c > 0) ? fmaxf(acc[o] + bias[c-1], 0.f) : 0.f;
      ov = f2bf(lrn_one(v, pv));
    }
    outb[((b*64 + c)*64 + oy)*64 + cx] = ov;
  }
}

// ---------------- K7u (round-5/10 verified, 561us): conv 16x16 VALID via MFMA implicit GEMM.
// 64 oc x 96 px per block, acc[4][6]=96 AGPR, grid 1024, 2-barrier direct staging,
// af ring-4 distance-2 prefetch (seamless across chunks), bf depth-1. VGPR 120 ->
// 2 blocks/CU. [k7 line CLOSED: bigger acc (r2-3), 1-barrier T14 (r7-9), and
// smaller acc/more waves (r11) all measured worse. 49% MfmaUtil equilibrium.]
__global__ __launch_bounds__(192, 1) void k7u(const u16* __restrict__ inb, const u16* __restrict__ wpk,
                                              const float* __restrict__ b5, u16* __restrict__ y5){
  __shared__ __align__(16) u16 itile[7168];          // 14,336 B
  int bid = blockIdx.x;
  int och = bid & 15;                                // 64-oc group
  int rem = bid >> 4;
  int n8  = rem & 7;
  int r   = rem >> 3;                                // 0..7
  int tid = threadIdx.x;
  int w = tid / 64, lane = tid & 63, quad = lane >> 4, m = lane & 15;
  int ic2q = quad >> 1, kyh = quad & 1;

  f32x4 acc[4][6];
  #pragma unroll
  for (int tm=0;tm<4;++tm)
    #pragma unroll
    for (int t=0;t<6;++t) acc[tm][t] = (f32x4){0.f,0.f,0.f,0.f};

  const u16* gin    = inb + ((size_t)n8 * 64) * 4096;
  const u16* wblock = wpk + ((size_t)(och >> 1) << 21) + (och & 1)*512;
  const u16* wbase  = wblock + quad*1024 + m*8;

  int bb = ((ic2q*7 + (2*w + kyh))*64 + m)*8;

  short8 af[4][4];                                   // ring-4, distance-2
  short8 bf[2][6];
  #pragma unroll
  for (int q=0;q<4;++q) af[0][q] = *(const short8*)(wbase + q*128);
  #pragma unroll
  for (int q=0;q<4;++q) af[1][q] = *(const short8*)(wbase + 4096 + q*128);

  #pragma unroll 1
  for (int chunk=0; chunk<32; ++chunk){
    __syncthreads();
    {
      const u16* gq = gin + (size_t)(chunk*2)*4096 + r*64;
      for (int v = tid; v < 1792; v += 192){           // 2 ic x 28 iy-pairs x 32 col-pairs
        int cp  = v & 31;
        int t2  = v >> 5;                              // 0..55
        int iyp = t2 % 28;
        int ic2 = t2 / 28;
        int iy0 = iyp*2;
        const u16* g = gq + ic2*4096 + iy0*64 + 2*cp;
        u32 d0 = *(const u32*)(g);
        u32 d1 = *(const u32*)(g + 64);
        u32 lo = (d0 & 0xffffu) | (d1 << 16);          // col 2cp:   rows iy0, iy0+1
        u32 hi = (d0 >> 16) | (d1 & 0xffff0000u);      // col 2cp+1
        int win = iy0 >> 3, j = iy0 & 7;
        int base = ((ic2*7 + win)*64 + 2*cp)*8 + j;
        *(u32*)&itile[base]     = lo;
        *(u32*)&itile[base + 8] = hi;
      }
    }
    __syncthreads();
    const u16* wk0  = wbase + (chunk << 16);
    const u16* bptr = itile + bb;

    #pragma unroll
    for (int t=0;t<6;++t) bf[0][t] = *(const short8*)(bptr + (t%3)*128 + (t/3)*512);

    #pragma unroll
    for (int kx=0; kx<16; ++kx){
      #pragma unroll
      for (int q=0;q<4;++q) af[(kx+2)&3][q] = *(const short8*)(wk0 + (kx+2)*4096 + q*128);
      if (kx < 15){
        #pragma unroll
        for (int t=0;t<6;++t) bf[(kx+1)&1][t] = *(const short8*)(bptr + (t%3)*128 + (t/3)*512 + (kx+1)*8);
      }
      __builtin_amdgcn_s_setprio(1);
      #pragma unroll
      for (int q=0;q<4;++q)
        #pragma unroll
        for (int t=0;t<6;++t)
          acc[q][t] = __builtin_amdgcn_mfma_f32_16x16x32_bf16(af[kx&3][q], bf[kx&1][t], acc[q][t], 0, 0, 0);
      __builtin_amdgcn_s_setprio(0);
    }
  }

  #pragma unroll
  for (int tm=0;tm<4;++tm){
    #pragma unroll
    for (int rr=0;rr<4;++rr){
      int oc = och*64 + tm*16 + quad*4 + rr;
      float bias = b5[oc];
      #pragma unroll
      for (int t=0;t<6;++t){
        int row = r + 16*w + 8*(t/3);
        int ox  = (t%3)*16 + m;
        float v = acc[tm][t][rr] + bias;
        v = v>0.f ? v : 0.f;
        y5[(((size_t)n8*1024 + oc)*48 + row)*48 + ox] = f2bf(v);
      }
    }
  }
}

// ---------------- K8a: 1x1 conv (1024->1024) MFMA + relu + w7-dot + block reduce + atomicAdd
__global__ __launch_bounds__(128) void k8a(const u16* __restrict__ y5, const u16* __restrict__ w6pk,
                                           const float* __restrict__ b6, const float* __restrict__ w7,
                                           float* __restrict__ accum){
  __shared__ __align__(16) u16 btile[96*136];        // 26,112 B
  __shared__ float red[8*96];
  int bid = blockIdx.x;
  int mb = bid & 7;
  int r  = bid >> 3;
  int n8 = r / 24, rp = r % 24;
  int r0 = 2*rp;
  int tid = threadIdx.x;
  int w = tid >> 6, lane = tid & 63, quad = lane >> 4, m = lane & 15;

  f32x4 acc[4][6];
  #pragma unroll
  for (int tm=0;tm<4;++tm)
    #pragma unroll
    for (int t=0;t<6;++t) acc[tm][t] = (f32x4){0.f,0.f,0.f,0.f};

  #pragma unroll 1
  for (int kc=0; kc<8; ++kc){
    __syncthreads();
    for (int u=tid; u<6144; u+=128){                 // 128 ic x 48 px-pairs
      int pp = u % 48; int ic2 = u / 48;
      int rowl = pp / 24; int ox0 = (pp % 24)*2;
      u32 val = *(const u32*)(y5 + (((size_t)(n8*1024 + kc*128 + ic2)*48) + r0 + rowl)*48 + ox0);
      int px = rowl*48 + ox0;
      btile[(px  )*136 + ic2] = (u16)(val & 0xffffu);
      btile[(px+1)*136 + ic2] = (u16)(val >> 16);
    }
    __syncthreads();
    for (int kk=0; kk<4; ++kk){
      short8 af[4];
      #pragma unroll
      for (int tm=0;tm<4;++tm)
        af[tm] = *(const short8*)(w6pk + (size_t)((((mb*8 + kc)*4 + kk)*4 + quad)*128 + (w*64 + tm*16 + m))*8);
      short8 bf[6];
      #pragma unroll
      for (int t=0;t<6;++t){
        int pxl = ((t>=3)?48:0) + (t%3)*16 + m;
        bf[t] = *(const short8*)(btile + pxl*136 + kk*32 + quad*8);
      }
      #pragma unroll
      for (int tm=0;tm<4;++tm)
        #pragma unroll
        for (int t=0;t<6;++t)
          acc[tm][t] = __builtin_amdgcn_mfma_f32_16x16x32_bf16(af[tm], bf[t], acc[tm][t], 0, 0, 0);
    }
  }
  float part[6];
  #pragma unroll
  for (int t=0;t<6;++t) part[t]=0.f;
  #pragma unroll
  for (int tm=0;tm<4;++tm){
    #pragma unroll
    for (int rr=0;rr<4;++rr){
      int oc = mb*128 + w*64 + tm*16 + quad*4 + rr;
      float bb = b6[oc];
      float ww = w7[oc];
      #pragma unroll
      for (int t=0;t<6;++t){
        float z = acc[tm][t][rr] + bb;
        z = z>0.f ? z : 0.f;
        part[t] += ww*z;
      }
    }
  }
  #pragma unroll
  for (int t=0;t<6;++t){
    int pxl = ((t>=3)?48:0) + (t%3)*16 + m;
    red[(w*4+quad)*96 + pxl] = part[t];
  }
  __syncthreads();
  if (tid < 96){
    float s = 0.f;
    #pragma unroll
    for (int k=0;k<8;++k) s += red[k*96 + tid];
    int rowl = tid / 48, ox = tid % 48;
    atomicAdd(&accum[((size_t)n8*48 + r0 + rowl)*48 + ox], s);
  }
}

// ---------------- K8b: sigmoid + interweave. accum (8,48,48) -> out (2,1,96,96) f32
__global__ __launch_bounds__(256) void k8b(const float* __restrict__ accum, const float* __restrict__ b7,
                                           float* __restrict__ out){
  int idx = blockIdx.x*256 + threadIdx.x;
  if (idx >= 18432) return;
  int n8 = idx / 2304; int rem = idx % 2304;
  int oy = rem / 48, ox = rem % 48;
  float s = accum[idx] + b7[0];
  float sig = 1.f / (1.f + expf(-s));
  int v = n8 >> 1, n = n8 & 1;
  int a = v & 1, bcol = v >> 1;
  out[((size_t)n*96 + 2*oy + a)*96 + 2*ox + bcol] = sig;
}

extern "C" void kernel_launch(void* const* d_in, const int* in_sizes, int n_in,
                              void* d_out, int out_size, void* d_ws, size_t ws_size,
                              hipStream_t stream){
  const float* x  = (const float*)d_in[0];
  const float* w1 = (const float*)d_in[1];
  const float* b1 = (const float*)d_in[2];
  const float* w2 = (const float*)d_in[3];
  const float* b2 = (const float*)d_in[4];
  const float* w3 = (const float*)d_in[5];
  const float* b3 = (const float*)d_in[6];
  const float* w4 = (const float*)d_in[7];
  const float* b4 = (const float*)d_in[8];
  const float* w5 = (const float*)d_in[9];
  const float* b5 = (const float*)d_in[10];
  const float* w6 = (const float*)d_in[11];
  const float* b6 = (const float*)d_in[12];
  const float* w7 = (const float*)d_in[13];
  const float* b7 = (const float*)d_in[14];
  float* ws = (float*)d_ws;
  float* out = (float*)d_out;

  // single verified layout (<= 82 MB):
  // C [0, 2,097,152) f32 ; Cb (u16) over C ; A [2,097,152, 4,194,304) ; B [4,194,304, 6,291,456)
  // F (u16) [2,097,152, 11,534,336) over dead A/B ; Wpk5 (u16) [11,534,336, 19,922,944)
  // W6pk (u16) [19,922,944, 20,447,232) ; accum [20,447,232, 20,465,664)
  float* C  = ws;
  u16*   Cb = (u16*)ws;
  float* A  = ws + 2097152;
  float* B  = ws + 4194304;
  u16*   F    = (u16*)(ws + 2097152);
  u16*   Wpk5 = (u16*)(ws + 11534336);
  u16*   W6pk = (u16*)(ws + 19922944);
  float* accum = ws + 20447232;

  hipLaunchKernelGGL(k0all,           dim3(69704), dim3(256), 0, stream, w5, Wpk5, w6, W6pk, accum);
  hipLaunchKernelGGL(k1_conv7x7,      dim3(8192),  dim3(256), 0, stream, x, w1, b1, A);
  hipLaunchKernelGGL(k2_conv5x5,      dim3(512),   dim3(256), 0, stream, A, w2, b2, B);
  hipLaunchKernelGGL(k3_lrn_crop_pool,dim3(7938),  dim3(256), 0, stream, B, C);
  hipLaunchKernelGGL(k_conv3x3,       dim3(1024),  dim3(256), 0, stream, C, w3, b3, A);
  hipLaunchKernelGGL(k5_fused,        dim3(1024),  dim3(256), 0, stream, A, w4, b4, Cb);
  hipLaunchKernelGGL(k7u,             dim3(1024),  dim3(192), 0, stream, Cb, Wpk5, b5, F);
  hipLaunchKernelGGL(k8a,             dim3(1536),  dim3(128), 0, stream, F, W6pk, b6, w7, accum);
  hipLaunchKernelGGL(k8b,             dim3(72),    dim3(256), 0, stream, accum, b7, out);
}

// Round 14
// 1307.470 us; speedup vs baseline: 1.0802x; 1.0183x over previous
//
#include <hip/hip_runtime.h>

typedef unsigned short u16;
typedef unsigned int   u32;
typedef unsigned long long u64;
typedef short short8 __attribute__((ext_vector_type(8)));
typedef float f32x4  __attribute__((ext_vector_type(4)));

__device__ __forceinline__ u16 f2bf(float f){
  u32 u = __float_as_uint(f);
  u32 r = (u + 0x7fffu + ((u >> 16) & 1u)) >> 16;
  return (u16)r;
}
__device__ __forceinline__ float lrn_one(float v, float pv){
  float avg = 0.5f*(v*v + pv*pv);
  float d = 1.0f + 2e-5f*avg;
  return v * exp2f(-0.75f * log2f(d));   // d >= 1, safe
}

// ---------------- K0w5 v2: prepack w5 via LDS transpose — COALESCED both sides.
// (Old version read w5 at 64-B stride per lane: 1/16 line utilization -> ~1 GB
// effective traffic on a 67 MB HBM-resident array. Hidden ~400us: never in top-5
// because each graph iteration's k7u (556us) outranks it.)
// Block = (ocb, chunk, ocq): 32 oc x 2 ic x 16 ky x 16 kx.
// Read: per-oc 512 contiguous floats (coalesced). LDS: bf16 [oc2][ky][kx] padded
// (oc2*273 + ky*17 + kx) to break power-of-2 bank strides. Write: 256-contiguous
// u16 runs per (kx,quad) (coalesced). Values/indexing identical to the original.
__global__ __launch_bounds__(256) void k0w5v2(const float* __restrict__ w5, u16* __restrict__ wpk){
  __shared__ u16 t[17470];                           // 34,940 B
  int b = blockIdx.x;                                // 1024 = 4 ocq x 32 chunk x 8 ocb
  int ocq   = b & 3;
  int chunk = (b >> 2) & 31;
  int ocb   = b >> 7;
  int tid = threadIdx.x;
  const float* src = w5 + ((size_t)(ocb*128 + ocq*32)*64 + chunk*2)*256;
  for (int v = tid; v < 16384; v += 256){
    int oc_l = v >> 9;                               // 0..31
    int r9   = v & 511;                              // ic_off*256 + ky*16 + kx
    float f = src[(size_t)oc_l*16384 + r9];
    int ic_off = r9 >> 8;
    int ky = (r9 >> 4) & 15;
    int kx = r9 & 15;
    t[(oc_l*2 + ic_off)*273 + ky*17 + kx] = f2bf(f);
  }
  __syncthreads();
  u16* dst = wpk + (((size_t)(ocb*32 + chunk)) << 16) + ocq*256;
  for (int v = tid; v < 16384; v += 256){
    int j    = v & 7;
    int oc_l = (v >> 3) & 31;
    int quad = (v >> 8) & 3;
    int kx   = v >> 10;
    u16 val = t[(oc_l*2 + (quad >> 1))*273 + ((quad & 1)*8 + j)*17 + kx];
    dst[((kx*4 + quad) << 10) + oc_l*8 + j] = val;
  }
}

// ---------------- K0rest: prepack w6 (fragment order) + zero accum.
// W6pk[mb(8)][kc(8)][kk(4)][quad(4)][oc128(128)][j(8)]  (coalesced af loads in k8a)
__global__ __launch_bounds__(256) void k0rest(const float* __restrict__ w6, u16* __restrict__ wpk6,
                                              float* __restrict__ accum){
  int b = blockIdx.x;
  if (b < 4096){
    int idx = b*256 + threadIdx.x;                   // 1,048,576
    int j     =  idx        & 7;
    int oc128 = (idx >> 3)  & 127;
    int quad  = (idx >> 10) & 3;
    int kk    = (idx >> 12) & 3;
    int kc    = (idx >> 14) & 7;
    int mb    =  idx >> 17;
    int oc = mb*128 + oc128;
    int ic = kc*128 + kk*32 + quad*8 + j;
    wpk6[idx] = f2bf(w6[oc*1024 + ic]);
  } else {
    int idx = (b - 4096)*256 + threadIdx.x;
    if (idx < 18432) accum[idx] = 0.f;
  }
}

// ---------------- K1: conv 7x7, 1->64, SAME pad 3, relu
__global__ __launch_bounds__(256) void k1_conv7x7(const float* __restrict__ x, const float* __restrict__ w1,
                                                  const float* __restrict__ b1, float* __restrict__ out){
  int idx = blockIdx.x*256 + threadIdx.x;            // 2,097,152
  int ox = idx & 127, oy = (idx>>7)&127, oc = (idx>>14)&63, n = idx>>20;
  float acc = b1[oc];
  const float* wb = w1 + oc*49;
  const float* xb = x + n*16384;
  #pragma unroll
  for (int ky=0;ky<7;++ky){
    int y = oy + ky - 3;
    if ((unsigned)y < 128u){
      #pragma unroll
      for (int kx=0;kx<7;++kx){
        int xx = ox + kx - 3;
        if ((unsigned)xx < 128u)
          acc += wb[ky*7+kx] * xb[y*128+xx];
      }
    }
  }
  out[idx] = acc > 0.f ? acc : 0.f;
}

// ---------------- K2 v4: conv 5x5, 64->64, SAME pad 2, relu. 8 oc per block.
__global__ __launch_bounds__(256) void k2_conv5x5(const float* __restrict__ in, const float* __restrict__ w2,
                                                  const float* __restrict__ b2, float* __restrict__ out){
  __shared__ __align__(16) float t[720];             // 20 rows x 36 cols
  __shared__ float wl[200];                          // 8 oc x 25
  int bid = blockIdx.x;
  int colg = bid & 3;
  int rowg = (bid >> 2) & 7;
  int ocg  = (bid >> 5) & 7;
  int n    =  bid >> 8;
  int tid = threadIdx.x;
  int oy0 = rowg*16, ox0 = colg*32;
  int r = tid >> 4, c0 = (tid & 15)*2;
  float acc[8][2];
  #pragma unroll
  for (int o=0;o<8;++o){ acc[o][0]=0.f; acc[o][1]=0.f; }

  for (int ic=0; ic<64; ++ic){
    __syncthreads();
    for (int u=tid; u<720; u+=256){
      int rr = u/36, cc = u - rr*36;
      int gy = oy0+rr-2, gx = ox0+cc-2;
      t[u] = ((unsigned)gy<128u && (unsigned)gx<128u) ? in[((n*64+ic)*128+gy)*128+gx] : 0.f;
    }
    if (tid < 200) wl[tid] = w2[((ocg*8 + tid/25)*64 + ic)*25 + (tid%25)];
    __syncthreads();
    #pragma unroll
    for (int ky=0;ky<5;++ky){
      float2 a = *(const float2*)&t[(r+ky)*36 + c0];
      float2 b = *(const float2*)&t[(r+ky)*36 + c0 + 2];
      float2 c = *(const float2*)&t[(r+ky)*36 + c0 + 4];
      float f[6] = {a.x,a.y,b.x,b.y,c.x,c.y};
      #pragma unroll
      for (int o=0;o<8;++o){
        #pragma unroll
        for (int kx=0;kx<5;++kx){
          float wv = wl[o*25 + ky*5 + kx];
          acc[o][0] += wv * f[kx];
          acc[o][1] += wv * f[kx+1];
        }
      }
    }
  }
  #pragma unroll
  for (int o=0;o<8;++o){
    float bb = b2[ocg*8 + o];
    float2 st;
    st.x = fmaxf(acc[o][0]+bb, 0.f);
    st.y = fmaxf(acc[o][1]+bb, 0.f);
    *(float2*)&out[((n*64 + ocg*8 + o)*128 + oy0+r)*128 + ox0 + c0] = st;
  }
}

// ---------------- K3: LRN + 4-crop + 2x2 maxpool
__global__ __launch_bounds__(256) void k3_lrn_crop_pool(const float* __restrict__ h, float* __restrict__ out){
  int idx = blockIdx.x*256 + threadIdx.x;            // 2,032,128
  int j = idx % 63; int t1 = idx / 63;
  int i = t1 % 63; int t2 = t1 / 63;
  int c = t2 & 63; int b = t2 >> 6;
  int v = b >> 1, n = b & 1;
  int r0 = v & 1, c0 = v >> 1;
  const float* base  = h + ((n*64+c  )*128)*128;
  const float* basep = h + ((n*64+c-1)*128)*128;
  float m = -3.4e38f;
  #pragma unroll
  for (int a=0;a<2;++a)
    #pragma unroll
    for (int bb=0;bb<2;++bb){
      int y = r0+2*i+a, xx = c0+2*j+bb;
      float val = base[y*128+xx];
      float pv  = c ? basep[y*128+xx] : 0.f;
      m = fmaxf(m, lrn_one(val, pv));
    }
  out[idx] = m;
}

// ---------------- K4 (v3): conv 3x3, 64->64, SAME pad 1, relu. 8 oc per block.
__global__ __launch_bounds__(256) void k_conv3x3(const float* __restrict__ in, const float* __restrict__ w,
                                                 const float* __restrict__ bias, float* __restrict__ out){
  __shared__ __align__(16) float t[408];             // 6 rows x 68 (66 used)
  __shared__ float wl[72];                           // 8 oc x 9
  int bid = blockIdx.x;
  int rowg = bid & 15;
  int ocg  = (bid >> 4) & 7;
  int b    =  bid >> 7;
  int tid = threadIdx.x;
  int r = tid >> 6, cx = tid & 63;                   // 4 rows x 64 cols (col 63 masked)
  int oy0 = rowg*4;
  float acc[8];
  #pragma unroll
  for (int o=0;o<8;++o) acc[o] = 0.f;

  for (int ic=0; ic<64; ++ic){
    __syncthreads();
    #pragma unroll
    for (int u0=0; u0<2; ++u0){
      int u = tid + u0*256;
      if (u < 408){
        int rr = u/68, cc = u - rr*68;
        int gy = oy0+rr-1, gx = cc-1;
        t[u] = (cc<66 && (unsigned)gy<63u && (unsigned)gx<63u) ? in[((b*64+ic)*63+gy)*63+gx] : 0.f;
      }
    }
    if (tid < 72) wl[tid] = w[((ocg*8 + tid/9)*64 + ic)*9 + (tid%9)];
    __syncthreads();
    #pragma unroll
    for (int ky=0;ky<3;++ky){
      float a0 = t[(r+ky)*68 + cx];
      float a1 = t[(r+ky)*68 + cx + 1];
      float a2 = t[(r+ky)*68 + cx + 2];
      #pragma unroll
      for (int o=0;o<8;++o){
        acc[o] += wl[o*9+ky*3  ]*a0;
        acc[o] += wl[o*9+ky*3+1]*a1;
        acc[o] += wl[o*9+ky*3+2]*a2;
      }
    }
  }
  int oy = oy0 + r;
  if (oy < 63 && cx < 63){
    #pragma unroll
    for (int o=0;o<8;++o){
      float v = acc[o] + bias[ocg*8+o];
      out[((b*64 + ocg*8 + o)*63 + oy)*63 + cx] = v > 0.f ? v : 0.f;
    }
  }
}

// ---------------- K5f: conv 3x3 (64->64) + relu + LRN + bf16 pack, fused (replaces k5+k6).
__global__ __launch_bounds__(256) void k5_fused(const float* __restrict__ in, const float* __restrict__ w,
                                                const float* __restrict__ bias, u16* __restrict__ outb){
  __shared__ __align__(16) float t[408];             // 6 rows x 68 (66 used)
  __shared__ float wl[81];                           // 9 ch x 9
  int bid = blockIdx.x;
  int rowg = bid & 15;
  int ocg  = (bid >> 4) & 7;
  int b    =  bid >> 7;
  int tid = threadIdx.x;
  int r = tid >> 6, cx = tid & 63;                   // 4 rows x 64 cols
  int oy0 = rowg*4;
  float acc[9];
  #pragma unroll
  for (int o=0;o<9;++o) acc[o] = 0.f;

  for (int ic=0; ic<64; ++ic){
    __syncthreads();
    #pragma unroll
    for (int u0=0; u0<2; ++u0){
      int u = tid + u0*256;
      if (u < 408){
        int rr = u/68, cc = u - rr*68;
        int gy = oy0+rr-1, gx = cc-1;
        t[u] = (cc<66 && (unsigned)gy<63u && (unsigned)gx<63u) ? in[((b*64+ic)*63+gy)*63+gx] : 0.f;
      }
    }
    if (tid < 81){
      int o = tid/9, k = tid - o*9;
      int c = ocg*8 - 1 + o;                         // channel index, may be -1
      wl[tid] = (c >= 0) ? w[(c*64 + ic)*9 + k] : 0.f;
    }
    __syncthreads();
    #pragma unroll
    for (int ky=0;ky<3;++ky){
      float a0 = t[(r+ky)*68 + cx];
      float a1 = t[(r+ky)*68 + cx + 1];
      float a2 = t[(r+ky)*68 + cx + 2];
      #pragma unroll
      for (int o=0;o<9;++o){
        acc[o] += wl[o*9+ky*3  ]*a0;
        acc[o] += wl[o*9+ky*3+1]*a1;
        acc[o] += wl[o*9+ky*3+2]*a2;
      }
    }
  }
  int oy = oy0 + r;                                  // 0..63
  bool valid = (oy < 63) && (cx < 63);
  #pragma unroll
  for (int o=0;o<8;++o){
    int c = ocg*8 + o;                               // output channel; acc idx o+1
    u16 ov = 0;
    if (valid){
      float v  = fmaxf(acc[o+1] + bias[c], 0.f);
      float pv = (c > 0) ? fmaxf(acc[o] + bias[c-1], 0.f) : 0.f;
      ov = f2bf(lrn_one(v, pv));
    }
    outb[((b*64 + c)*64 + oy)*64 + cx] = ov;
  }
}

// ---------------- K7u (round-5/10 verified, ~556us): conv 16x16 VALID via MFMA implicit GEMM.
// 64 oc x 96 px per block, acc[4][6]=96 AGPR, grid 1024, 2-barrier direct staging,
// af ring-4 distance-2 prefetch (seamless across chunks), bf depth-1. VGPR 120 ->
// 2 blocks/CU. [k7 line CLOSED: bigger acc (r2-3), 1-barrier T14 (r7-9), and
// smaller acc/more waves (r11) all measured worse. 49% MfmaUtil equilibrium.]
__global__ __launch_bounds__(192, 1) void k7u(const u16* __restrict__ inb, const u16* __restrict__ wpk,
                                              const float* __restrict__ b5, u16* __restrict__ y5){
  __shared__ __align__(16) u16 itile[7168];          // 14,336 B
  int bid = blockIdx.x;
  int och = bid & 15;                                // 64-oc group
  int rem = bid >> 4;
  int n8  = rem & 7;
  int r   = rem >> 3;                                // 0..7
  int tid = threadIdx.x;
  int w = tid / 64, lane = tid & 63, quad = lane >> 4, m = lane & 15;
  int ic2q = quad >> 1, kyh = quad & 1;

  f32x4 acc[4][6];
  #pragma unroll
  for (int tm=0;tm<4;++tm)
    #pragma unroll
    for (int t=0;t<6;++t) acc[tm][t] = (f32x4){0.f,0.f,0.f,0.f};

  const u16* gin    = inb + ((size_t)n8 * 64) * 4096;
  const u16* wblock = wpk + ((size_t)(och >> 1) << 21) + (och & 1)*512;
  const u16* wbase  = wblock + quad*1024 + m*8;

  int bb = ((ic2q*7 + (2*w + kyh))*64 + m)*8;

  short8 af[4][4];                                   // ring-4, distance-2
  short8 bf[2][6];
  #pragma unroll
  for (int q=0;q<4;++q) af[0][q] = *(const short8*)(wbase + q*128);
  #pragma unroll
  for (int q=0;q<4;++q) af[1][q] = *(const short8*)(wbase + 4096 + q*128);

  #pragma unroll 1
  for (int chunk=0; chunk<32; ++chunk){
    __syncthreads();
    {
      const u16* gq = gin + (size_t)(chunk*2)*4096 + r*64;
      for (int v = tid; v < 1792; v += 192){           // 2 ic x 28 iy-pairs x 32 col-pairs
        int cp  = v & 31;
        int t2  = v >> 5;                              // 0..55
        int iyp = t2 % 28;
        int ic2 = t2 / 28;
        int iy0 = iyp*2;
        const u16* g = gq + ic2*4096 + iy0*64 + 2*cp;
        u32 d0 = *(const u32*)(g);
        u32 d1 = *(const u32*)(g + 64);
        u32 lo = (d0 & 0xffffu) | (d1 << 16);          // col 2cp:   rows iy0, iy0+1
        u32 hi = (d0 >> 16) | (d1 & 0xffff0000u);      // col 2cp+1
        int win = iy0 >> 3, j = iy0 & 7;
        int base = ((ic2*7 + win)*64 + 2*cp)*8 + j;
        *(u32*)&itile[base]     = lo;
        *(u32*)&itile[base + 8] = hi;
      }
    }
    __syncthreads();
    const u16* wk0  = wbase + (chunk << 16);
    const u16* bptr = itile + bb;

    #pragma unroll
    for (int t=0;t<6;++t) bf[0][t] = *(const short8*)(bptr + (t%3)*128 + (t/3)*512);

    #pragma unroll
    for (int kx=0; kx<16; ++kx){
      #pragma unroll
      for (int q=0;q<4;++q) af[(kx+2)&3][q] = *(const short8*)(wk0 + (kx+2)*4096 + q*128);
      if (kx < 15){
        #pragma unroll
        for (int t=0;t<6;++t) bf[(kx+1)&1][t] = *(const short8*)(bptr + (t%3)*128 + (t/3)*512 + (kx+1)*8);
      }
      __builtin_amdgcn_s_setprio(1);
      #pragma unroll
      for (int q=0;q<4;++q)
        #pragma unroll
        for (int t=0;t<6;++t)
          acc[q][t] = __builtin_amdgcn_mfma_f32_16x16x32_bf16(af[kx&3][q], bf[kx&1][t], acc[q][t], 0, 0, 0);
      __builtin_amdgcn_s_setprio(0);
    }
  }

  #pragma unroll
  for (int tm=0;tm<4;++tm){
    #pragma unroll
    for (int rr=0;rr<4;++rr){
      int oc = och*64 + tm*16 + quad*4 + rr;
      float bias = b5[oc];
      #pragma unroll
      for (int t=0;t<6;++t){
        int row = r + 16*w + 8*(t/3);
        int ox  = (t%3)*16 + m;
        float v = acc[tm][t][rr] + bias;
        v = v>0.f ? v : 0.f;
        y5[(((size_t)n8*1024 + oc)*48 + row)*48 + ox] = f2bf(v);
      }
    }
  }
}

// ---------------- K8a: 1x1 conv (1024->1024) MFMA + relu + w7-dot + block reduce + atomicAdd
__global__ __launch_bounds__(128) void k8a(const u16* __restrict__ y5, const u16* __restrict__ w6pk,
                                           const float* __restrict__ b6, const float* __restrict__ w7,
                                           float* __restrict__ accum){
  __shared__ __align__(16) u16 btile[96*136];        // 26,112 B
  __shared__ float red[8*96];
  int bid = blockIdx.x;
  int mb = bid & 7;
  int r  = bid >> 3;
  int n8 = r / 24, rp = r % 24;
  int r0 = 2*rp;
  int tid = threadIdx.x;
  int w = tid >> 6, lane = tid & 63, quad = lane >> 4, m = lane & 15;

  f32x4 acc[4][6];
  #pragma unroll
  for (int tm=0;tm<4;++tm)
    #pragma unroll
    for (int t=0;t<6;++t) acc[tm][t] = (f32x4){0.f,0.f,0.f,0.f};

  #pragma unroll 1
  for (int kc=0; kc<8; ++kc){
    __syncthreads();
    for (int u=tid; u<6144; u+=128){                 // 128 ic x 48 px-pairs
      int pp = u % 48; int ic2 = u / 48;
      int rowl = pp / 24; int ox0 = (pp % 24)*2;
      u32 val = *(const u32*)(y5 + (((size_t)(n8*1024 + kc*128 + ic2)*48) + r0 + rowl)*48 + ox0);
      int px = rowl*48 + ox0;
      btile[(px  )*136 + ic2] = (u16)(val & 0xffffu);
      btile[(px+1)*136 + ic2] = (u16)(val >> 16);
    }
    __syncthreads();
    for (int kk=0; kk<4; ++kk){
      short8 af[4];
      #pragma unroll
      for (int tm=0;tm<4;++tm)
        af[tm] = *(const short8*)(w6pk + (size_t)((((mb*8 + kc)*4 + kk)*4 + quad)*128 + (w*64 + tm*16 + m))*8);
      short8 bf[6];
      #pragma unroll
      for (int t=0;t<6;++t){
        int pxl = ((t>=3)?48:0) + (t%3)*16 + m;
        bf[t] = *(const short8*)(btile + pxl*136 + kk*32 + quad*8);
      }
      #pragma unroll
      for (int tm=0;tm<4;++tm)
        #pragma unroll
        for (int t=0;t<6;++t)
          acc[tm][t] = __builtin_amdgcn_mfma_f32_16x16x32_bf16(af[tm], bf[t], acc[tm][t], 0, 0, 0);
    }
  }
  float part[6];
  #pragma unroll
  for (int t=0;t<6;++t) part[t]=0.f;
  #pragma unroll
  for (int tm=0;tm<4;++tm){
    #pragma unroll
    for (int rr=0;rr<4;++rr){
      int oc = mb*128 + w*64 + tm*16 + quad*4 + rr;
      float bb = b6[oc];
      float ww = w7[oc];
      #pragma unroll
      for (int t=0;t<6;++t){
        float z = acc[tm][t][rr] + bb;
        z = z>0.f ? z : 0.f;
        part[t] += ww*z;
      }
    }
  }
  #pragma unroll
  for (int t=0;t<6;++t){
    int pxl = ((t>=3)?48:0) + (t%3)*16 + m;
    red[(w*4+quad)*96 + pxl] = part[t];
  }
  __syncthreads();
  if (tid < 96){
    float s = 0.f;
    #pragma unroll
    for (int k=0;k<8;++k) s += red[k*96 + tid];
    int rowl = tid / 48, ox = tid % 48;
    atomicAdd(&accum[((size_t)n8*48 + r0 + rowl)*48 + ox], s);
  }
}

// ---------------- K8b: sigmoid + interweave. accum (8,48,48) -> out (2,1,96,96) f32
__global__ __launch_bounds__(256) void k8b(const float* __restrict__ accum, const float* __restrict__ b7,
                                           float* __restrict__ out){
  int idx = blockIdx.x*256 + threadIdx.x;
  if (idx >= 18432) return;
  int n8 = idx / 2304; int rem = idx % 2304;
  int oy = rem / 48, ox = rem % 48;
  float s = accum[idx] + b7[0];
  float sig = 1.f / (1.f + expf(-s));
  int v = n8 >> 1, n = n8 & 1;
  int a = v & 1, bcol = v >> 1;
  out[((size_t)n*96 + 2*oy + a)*96 + 2*ox + bcol] = sig;
}

extern "C" void kernel_launch(void* const* d_in, const int* in_sizes, int n_in,
                              void* d_out, int out_size, void* d_ws, size_t ws_size,
                              hipStream_t stream){
  const float* x  = (const float*)d_in[0];
  const float* w1 = (const float*)d_in[1];
  const float* b1 = (const float*)d_in[2];
  const float* w2 = (const float*)d_in[3];
  const float* b2 = (const float*)d_in[4];
  const float* w3 = (const float*)d_in[5];
  const float* b3 = (const float*)d_in[6];
  const float* w4 = (const float*)d_in[7];
  const float* b4 = (const float*)d_in[8];
  const float* w5 = (const float*)d_in[9];
  const float* b5 = (const float*)d_in[10];
  const float* w6 = (const float*)d_in[11];
  const float* b6 = (const float*)d_in[12];
  const float* w7 = (const float*)d_in[13];
  const float* b7 = (const float*)d_in[14];
  float* ws = (float*)d_ws;
  float* out = (float*)d_out;

  // single verified layout (<= 82 MB):
  // C [0, 2,097,152) f32 ; Cb (u16) over C ; A [2,097,152, 4,194,304) ; B [4,194,304, 6,291,456)
  // F (u16) [2,097,152, 11,534,336) over dead A/B ; Wpk5 (u16) [11,534,336, 19,922,944)
  // W6pk (u16) [19,922,944, 20,447,232) ; accum [20,447,232, 20,465,664)
  float* C  = ws;
  u16*   Cb = (u16*)ws;
  float* A  = ws + 2097152;
  float* B  = ws + 4194304;
  u16*   F    = (u16*)(ws + 2097152);
  u16*   Wpk5 = (u16*)(ws + 11534336);
  u16*   W6pk = (u16*)(ws + 19922944);
  float* accum = ws + 20447232;

  hipLaunchKernelGGL(k0w5v2,          dim3(1024),  dim3(256), 0, stream, w5, Wpk5);
  hipLaunchKernelGGL(k0rest,          dim3(4168),  dim3(256), 0, stream, w6, W6pk, accum);
  hipLaunchKernelGGL(k1_conv7x7,      dim3(8192),  dim3(256), 0, stream, x, w1, b1, A);
  hipLaunchKernelGGL(k2_conv5x5,      dim3(512),   dim3(256), 0, stream, A, w2, b2, B);
  hipLaunchKernelGGL(k3_lrn_crop_pool,dim3(7938),  dim3(256), 0, stream, B, C);
  hipLaunchKernelGGL(k_conv3x3,       dim3(1024),  dim3(256), 0, stream, C, w3, b3, A);
  hipLaunchKernelGGL(k5_fused,        dim3(1024),  dim3(256), 0, stream, A, w4, b4, Cb);
  hipLaunchKernelGGL(k7u,             dim3(1024),  dim3(192), 0, stream, Cb, Wpk5, b5, F);
  hipLaunchKernelGGL(k8a,             dim3(1536),  dim3(128), 0, stream, F, W6pk, b6, w7, accum);
  hipLaunchKernelGGL(k8b,             dim3(72),    dim3(256), 0, stream, accum, b7, out);
}